// Round 5
// baseline (702.781 us; speedup 1.0000x reference)
//
#include <hip/hip_runtime.h>
#include <hip/hip_bf16.h>
#include <math.h>

// Problem constants (B=2,S=512 -> T=1024)
#define T_    1024
#define H_    2048
#define E_    64
#define I_    1024
#define TOPK  8
#define CAP   1024        // max rows per expert (worst case)

// GEMM tiling (both gemms): 192 token-rows x 64 out-cols, K-chunk 32
#define GTM   192
#define GTN   64
#define GBK   32

typedef __attribute__((ext_vector_type(8))) short  short8;
typedef __attribute__((ext_vector_type(8))) __bf16 bf16x8;
typedef __attribute__((ext_vector_type(4))) float  f32x4;

__device__ __forceinline__ unsigned short f2bf(float f) {
  unsigned int u = __float_as_uint(f);
  u += 0x7FFFu + ((u >> 16) & 1u);   // RNE
  return (unsigned short)(u >> 16);
}

// pack two fp32 -> [bf16(lo) | bf16(hi)<<16] (round-half-up, 0.5ulp)
__device__ __forceinline__ unsigned int pack2bf(float lo, float hi) {
  const unsigned int a = __float_as_uint(hi) + 0x8000u;
  const unsigned int b = __float_as_uint(lo) + 0x8000u;
  return __builtin_amdgcn_perm(a, b, 0x07060302u);
}

__device__ __forceinline__ f32x4 mfma16(short8 a, short8 b, f32x4 c) {
  return __builtin_amdgcn_mfma_f32_16x16x32_bf16(
      __builtin_bit_cast(bf16x8, a), __builtin_bit_cast(bf16x8, b), c, 0, 0, 0);
}

// async global->LDS, 16B per lane. LDS dest must be wave-uniform base + lane*16.
__device__ __forceinline__ void gload16(const void* g, void* lds) {
  auto gp = reinterpret_cast<const __attribute__((address_space(1))) unsigned int*>(
      reinterpret_cast<uintptr_t>(g));
  auto lp = reinterpret_cast<__attribute__((address_space(3))) unsigned int*>(
      static_cast<unsigned int>(reinterpret_cast<uintptr_t>(lds)));
  __builtin_amdgcn_global_load_lds(gp, lp, 16, 0, 0);
}

// build a bf16x8 fragment from two float4s (8 consecutive k-elements)
__device__ __forceinline__ short8 cvt_frag(float4 lo, float4 hi) {
  uint4 u;
  u.x = pack2bf(lo.x, lo.y); u.y = pack2bf(lo.z, lo.w);
  u.z = pack2bf(hi.x, hi.y); u.w = pack2bf(hi.z, hi.w);
  return __builtin_bit_cast(short8, u);
}

// ---------------------------------------------------------------------------
// Kernel 1: router. One block per 4 tokens (grid 256). rw row fetched once
// per block, reused x4 in registers. Wave w does softmax+top8 of token t0+w.
// ---------------------------------------------------------------------------
__global__ __launch_bounds__(256) void router_k(
    const float* __restrict__ x, const float* __restrict__ rw,
    float* __restrict__ topw, int* __restrict__ counts, int* __restrict__ rows)
{
  __shared__ float xs[4][H_];   // 32 KB
  __shared__ float lg[4][E_];
  const int t0  = blockIdx.x * 4;
  const int tid = threadIdx.x;
  for (int q = tid; q < 4 * (H_ / 4); q += 256) {
    const int tt = q >> 9;              // H_/4 = 512 float4 per row
    const int c  = q & 511;
    ((float4*)xs[tt])[c] = ((const float4*)(x + (size_t)(t0 + tt) * H_))[c];
  }
  __syncthreads();

  const int w = tid >> 6, lane = tid & 63;
  for (int ee = 0; ee < 16; ++ee) {
    const int e = w * 16 + ee;
    const float* wr = rw + (size_t)e * H_;
    float s0 = 0.f, s1 = 0.f, s2 = 0.f, s3 = 0.f;
    for (int h = lane; h < H_; h += 64) {
      const float wv = wr[h];
      s0 += wv * xs[0][h]; s1 += wv * xs[1][h];
      s2 += wv * xs[2][h]; s3 += wv * xs[3][h];
    }
    for (int off = 32; off; off >>= 1) {
      s0 += __shfl_xor(s0, off); s1 += __shfl_xor(s1, off);
      s2 += __shfl_xor(s2, off); s3 += __shfl_xor(s3, off);
    }
    if (lane == 0) { lg[0][e] = s0; lg[1][e] = s1; lg[2][e] = s2; lg[3][e] = s3; }
  }
  __syncthreads();

  {
    const int t = t0 + w;
    const float logit = lg[w][lane];
    float mx = logit;
    for (int off = 32; off; off >>= 1) mx = fmaxf(mx, __shfl_xor(mx, off));
    const float ex = expf(logit - mx);
    float sum = ex;
    for (int off = 32; off; off >>= 1) sum += __shfl_xor(sum, off);
    float p = ex / sum;
    for (int k = 0; k < TOPK; ++k) {
      float m = p; int mi = lane;
      for (int off = 32; off; off >>= 1) {
        const float om = __shfl_xor(m, off);
        const int   oi = __shfl_xor(mi, off);
        if (om > m || (om == m && oi < mi)) { m = om; mi = oi; }
      }
      if (lane == 0) {
        const int r = t * TOPK + k;
        topw[r] = m;
        const int pos = atomicAdd(&counts[mi], 1);
        rows[mi * CAP + pos] = r;
      }
      if (lane == mi) p = -1.f;
    }
  }
}

// ---------------------------------------------------------------------------
// Kernel 2: gate/up GEMM. Flat grid 1024 = E x (I/64), 512 threads (8 waves).
// XCD-clustered mapping: bid = (e%8) + 8*((e/8)*16 + n) -> all 16 n-blocks of
// an expert share one XCD's L2 (A-tile read once from HBM, then L2-hits).
// Single-buffered LDS, global_load_lds staging (linear dest, XOR-swz source).
// ---------------------------------------------------------------------------
__global__ __launch_bounds__(512, 4) void gateup_k(
    const float* __restrict__ x, const float* __restrict__ wg,
    const float* __restrict__ wu, const float* __restrict__ topw,
    const int* __restrict__ counts, const int* __restrict__ rows,
    unsigned short* __restrict__ hmid)
{
  const int bid = blockIdx.x;
  const int q_  = bid >> 3;
  const int e   = ((q_ >> 4) << 3) + (bid & 7);   // (e/8)*8 + e%8
  const int n0  = (q_ & 15) * GTN;
  const int cnt = counts[e];
  if (cnt == 0) return;
  const int* erows = rows + e * CAP;

  __shared__ __align__(16) float Al [GTM][GBK];   // 24KB
  __shared__ __align__(16) float Bgl[GTN][GBK];   // 8KB
  __shared__ __align__(16) float Bul[GTN][GBK];   // 8KB

  const int tid  = threadIdx.x;
  const int wid  = tid >> 6, lane = tid & 63;
  const int wm   = wid >> 1, wn = wid & 1;        // 4x2 waves: 48 rows x 32 cols

  const float* wgE = wg + (size_t)e * I_ * H_ + (size_t)n0 * H_;
  const float* wuE = wu + (size_t)e * I_ * H_ + (size_t)n0 * H_;

  // staging geometry (linear LDS dest; source chunk XOR-swizzled)
  int arow[3], acoff[3];
#pragma unroll
  for (int q = 0; q < 3; ++q) {
    const int row = q * 64 + wid * 8 + (lane >> 3);
    arow[q]  = row;
    acoff[q] = ((lane & 7) ^ (row & 7)) * 4;
  }
  const int brow  = wid * 8 + (lane >> 3);
  const int bcoff = ((lane & 7) ^ (brow & 7)) * 4;

  char* AlB = (char*)Al; char* BgB = (char*)Bgl; char* BuB = (char*)Bul;
  const int ldsLane = wid * 1024 + lane * 16;

  // fragment LDS offsets (float units)
  int aoff[3][2], boff[2][2];
  const int h = lane >> 4;
#pragma unroll
  for (int mi = 0; mi < 3; ++mi) {
    const int r = wm * 48 + mi * 16 + (lane & 15);
    aoff[mi][0] = r * GBK + (((2*h    ) ^ (r & 7)) * 4);
    aoff[mi][1] = r * GBK + (((2*h + 1) ^ (r & 7)) * 4);
  }
#pragma unroll
  for (int ni = 0; ni < 2; ++ni) {
    const int r = wn * 32 + ni * 16 + (lane & 15);
    boff[ni][0] = r * GBK + (((2*h    ) ^ (r & 7)) * 4);
    boff[ni][1] = r * GBK + (((2*h + 1) ^ (r & 7)) * 4);
  }

  for (int m0 = 0; m0 < cnt; m0 += GTM) {
    const float* pa[3];
#pragma unroll
    for (int q = 0; q < 3; ++q) {
      int idx = m0 + arow[q]; if (idx >= cnt) idx = cnt - 1;
      pa[q] = x + (size_t)(erows[idx] >> 3) * H_ + acoff[q];
    }
    const float* pg = wgE + (size_t)brow * H_ + bcoff;
    const float* pu = wuE + (size_t)brow * H_ + bcoff;

    f32x4 accg[3][2], accu[3][2];
#pragma unroll
    for (int i = 0; i < 3; ++i)
#pragma unroll
      for (int j = 0; j < 2; ++j)
#pragma unroll
        for (int q = 0; q < 4; ++q) { accg[i][j][q] = 0.f; accu[i][j][q] = 0.f; }

    for (int k0 = 0; k0 < H_; k0 += GBK) {
      __syncthreads();                      // prev-iter reads done
      gload16(pa[0], AlB +     0 + ldsLane);
      gload16(pa[1], AlB +  8192 + ldsLane);
      gload16(pa[2], AlB + 16384 + ldsLane);
      gload16(pg,    BgB + ldsLane);
      gload16(pu,    BuB + ldsLane);
      pa[0] += GBK; pa[1] += GBK; pa[2] += GBK; pg += GBK; pu += GBK;
      __syncthreads();                      // vmcnt drained -> tile visible

      short8 af[3];
#pragma unroll
      for (int mi = 0; mi < 3; ++mi) {
        const float4 lo = *(const float4*)&((const float*)Al)[aoff[mi][0]];
        const float4 hi = *(const float4*)&((const float*)Al)[aoff[mi][1]];
        af[mi] = cvt_frag(lo, hi);
      }
#pragma unroll
      for (int ni = 0; ni < 2; ++ni) {
        const float4 glo = *(const float4*)&((const float*)Bgl)[boff[ni][0]];
        const float4 ghi = *(const float4*)&((const float*)Bgl)[boff[ni][1]];
        const short8 bg = cvt_frag(glo, ghi);
        const float4 ulo = *(const float4*)&((const float*)Bul)[boff[ni][0]];
        const float4 uhi = *(const float4*)&((const float*)Bul)[boff[ni][1]];
        const short8 bu = cvt_frag(ulo, uhi);
#pragma unroll
        for (int mi = 0; mi < 3; ++mi) {
          accg[mi][ni] = mfma16(af[mi], bg, accg[mi][ni]);
          accu[mi][ni] = mfma16(af[mi], bu, accu[mi][ni]);
        }
      }
    }
    // epilogue: h = silu(g)*u*cw -> bf16
#pragma unroll
    for (int mi = 0; mi < 3; ++mi)
#pragma unroll
      for (int ni = 0; ni < 2; ++ni)
#pragma unroll
        for (int j = 0; j < 4; ++j) {
          const int ml = wm * 48 + mi * 16 + (lane >> 4) * 4 + j;
          if (m0 + ml < cnt) {
            const int r = erows[m0 + ml];
            const float cw = topw[r];
            const float g = accg[mi][ni][j], uu = accu[mi][ni][j];
            const float hv = g / (1.f + __expf(-g)) * uu * cw;
            hmid[(size_t)r * I_ + n0 + wn * 32 + ni * 16 + (lane & 15)] = f2bf(hv);
          }
        }
  }
}

// ---------------------------------------------------------------------------
// Kernel 3: down GEMM. Flat grid 2048 = E x (H/64), XCD-clustered:
// bid = (e%8) + 8*((e/8)*32 + n). Single-buffered, same staging scheme.
// ---------------------------------------------------------------------------
__global__ __launch_bounds__(512, 4) void down_k(
    const unsigned short* __restrict__ hmid, const float* __restrict__ wd,
    const int* __restrict__ counts, const int* __restrict__ rows,
    float* __restrict__ outp, const int atomicMode)
{
  const int bid = blockIdx.x;
  const int q_  = bid >> 3;
  const int e   = ((q_ >> 5) << 3) + (bid & 7);
  const int n0  = (q_ & 31) * GTN;
  const int cnt = counts[e];
  if (cnt == 0) return;
  const int* erows = rows + e * CAP;

  __shared__ __align__(16) unsigned short Al[GTM][GBK];  // 12KB
  __shared__ __align__(16) float          Bl[GTN][GBK];  // 8KB

  const int tid  = threadIdx.x;
  const int wid  = tid >> 6, lane = tid & 63;
  const int wm   = wid >> 1, wn = wid & 1;

  const float* wdE = wd + (size_t)e * H_ * I_ + (size_t)n0 * I_;

  const int arow0 = wid * 16 + (lane >> 2);
  const int arow1 = 128 + arow0;
  const int ac0 = (((lane & 3) ^ ((arow0 >> 1) & 3))) * 8;  // ushort offset
  const int ac1 = (((lane & 3) ^ ((arow1 >> 1) & 3))) * 8;
  const int brow  = wid * 8 + (lane >> 3);
  const int bcoff = ((lane & 7) ^ (brow & 7)) * 4;

  char* AlB = (char*)Al; char* BlB = (char*)Bl;
  const int ldsLane = wid * 1024 + lane * 16;

  int aoff[3], boff[2][2];
  const int h = lane >> 4;
#pragma unroll
  for (int mi = 0; mi < 3; ++mi) {
    const int r = wm * 48 + mi * 16 + (lane & 15);
    aoff[mi] = r * GBK + ((h ^ ((r >> 1) & 3)) * 8);        // ushort units
  }
#pragma unroll
  for (int ni = 0; ni < 2; ++ni) {
    const int r = wn * 32 + ni * 16 + (lane & 15);
    boff[ni][0] = r * GBK + (((2*h    ) ^ (r & 7)) * 4);
    boff[ni][1] = r * GBK + (((2*h + 1) ^ (r & 7)) * 4);
  }

  for (int m0 = 0; m0 < cnt; m0 += GTM) {
    int i0 = m0 + arow0; if (i0 >= cnt) i0 = cnt - 1;
    int i1 = m0 + arow1; if (i1 >= cnt) i1 = cnt - 1;
    const unsigned short* pa0 = hmid + (size_t)erows[i0] * I_ + ac0;
    const unsigned short* pa1 = hmid + (size_t)erows[i1] * I_ + ac1;
    const float* pb = wdE + (size_t)brow * I_ + bcoff;

    f32x4 acc[3][2];
#pragma unroll
    for (int i = 0; i < 3; ++i)
#pragma unroll
      for (int j = 0; j < 2; ++j)
#pragma unroll
        for (int q = 0; q < 4; ++q) acc[i][j][q] = 0.f;

    for (int k0 = 0; k0 < I_; k0 += GBK) {
      __syncthreads();
      gload16(pa0, AlB + ldsLane);
      if (wid < 4) gload16(pa1, AlB + 8192 + ldsLane);
      gload16(pb, BlB + ldsLane);
      pa0 += GBK; pa1 += GBK; pb += GBK;
      __syncthreads();

      short8 af[3];
#pragma unroll
      for (int mi = 0; mi < 3; ++mi)
        af[mi] = *(const short8*)&((const unsigned short*)Al)[aoff[mi]];
#pragma unroll
      for (int ni = 0; ni < 2; ++ni) {
        const float4 blo = *(const float4*)&((const float*)Bl)[boff[ni][0]];
        const float4 bhi = *(const float4*)&((const float*)Bl)[boff[ni][1]];
        const short8 bw = cvt_frag(blo, bhi);
#pragma unroll
        for (int mi = 0; mi < 3; ++mi)
          acc[mi][ni] = mfma16(af[mi], bw, acc[mi][ni]);
      }
    }
#pragma unroll
    for (int mi = 0; mi < 3; ++mi)
#pragma unroll
      for (int ni = 0; ni < 2; ++ni)
#pragma unroll
        for (int j = 0; j < 4; ++j) {
          const int ml = wm * 48 + mi * 16 + (lane >> 4) * 4 + j;
          if (m0 + ml < cnt) {
            const int r = erows[m0 + ml];
            const int col = n0 + wn * 32 + ni * 16 + (lane & 15);
            if (atomicMode) atomicAdd(&outp[(size_t)(r >> 3) * H_ + col], acc[mi][ni][j]);
            else            outp[(size_t)r * H_ + col] = acc[mi][ni][j];
          }
        }
  }
}

// ---------------------------------------------------------------------------
// Kernel 4: combine partials over k=0..7 (deterministic fixed-order sum)
// ---------------------------------------------------------------------------
__global__ __launch_bounds__(256) void combine_k(
    const float* __restrict__ partial, float* __restrict__ out)
{
  const int idx = blockIdx.x * 256 + threadIdx.x;
  const int t = idx >> 9;
  const int c = idx & 511;
  float4 s; s.x = 0.f; s.y = 0.f; s.z = 0.f; s.w = 0.f;
#pragma unroll
  for (int k = 0; k < TOPK; ++k) {
    const float4 v = *(const float4*)(partial + (size_t)(t * TOPK + k) * H_ + c * 4);
    s.x += v.x; s.y += v.y; s.z += v.z; s.w += v.w;
  }
  *(float4*)(out + (size_t)t * H_ + c * 4) = s;
}

// ---------------------------------------------------------------------------
extern "C" void kernel_launch(void* const* d_in, const int* in_sizes, int n_in,
                              void* d_out, int out_size, void* d_ws, size_t ws_size,
                              hipStream_t stream)
{
  const float* x  = (const float*)d_in[0];
  const float* rw = (const float*)d_in[1];
  const float* wg = (const float*)d_in[2];
  const float* wu = (const float*)d_in[3];
  const float* wd = (const float*)d_in[4];
  float* out = (float*)d_out;

  char* ws = (char*)d_ws;
  const size_t OFF_TOPW = 1024;
  const size_t OFF_ROWS = OFF_TOPW + (size_t)T_ * TOPK * 4;
  const size_t OFF_HMID = OFF_ROWS + (size_t)E_ * CAP * 4;
  const size_t OFF_PART = OFF_HMID + (size_t)T_ * TOPK * I_ * 2;
  const size_t TOTAL    = OFF_PART + (size_t)T_ * TOPK * H_ * 4;

  int*   counts = (int*)ws;
  float* topw   = (float*)(ws + OFF_TOPW);
  int*   rows   = (int*)(ws + OFF_ROWS);
  unsigned short* hmid = (unsigned short*)(ws + OFF_HMID);
  float* partial = (float*)(ws + OFF_PART);

  const int usePartial = (ws_size >= TOTAL) ? 1 : 0;

  hipMemsetAsync(counts, 0, E_ * sizeof(int), stream);
  router_k<<<T_ / 4, 256, 0, stream>>>(x, rw, topw, counts, rows);
  gateup_k<<<E_ * (I_ / GTN), 512, 0, stream>>>(x, wg, wu, topw, counts, rows, hmid);
  if (usePartial) {
    down_k<<<E_ * (H_ / GTN), 512, 0, stream>>>(hmid, wd, counts, rows, partial, 0);
    combine_k<<<(T_ * H_ / 4) / 256, 256, 0, stream>>>(partial, out);
  } else {
    hipMemsetAsync(out, 0, (size_t)out_size * sizeof(float), stream);
    down_k<<<E_ * (H_ / GTN), 512, 0, stream>>>(hmid, wd, counts, rows, out, 1);
  }
}

// Round 6
// 676.599 us; speedup vs baseline: 1.0387x; 1.0387x over previous
//
#include <hip/hip_runtime.h>
#include <hip/hip_bf16.h>
#include <math.h>

// Problem constants (B=2,S=512 -> T=1024)
#define T_    1024
#define H_    2048
#define E_    64
#define I_    1024
#define TOPK  8
#define CAP   1024        // max rows per expert (worst case)

// GEMM tiling (both gemms): 192 token-rows x 64 out-cols, K-chunk 32
#define GTM   192
#define GTN   64
#define GBK   32

typedef __attribute__((ext_vector_type(8))) short  short8;
typedef __attribute__((ext_vector_type(8))) __bf16 bf16x8;
typedef __attribute__((ext_vector_type(4))) float  f32x4;

__device__ __forceinline__ unsigned short f2bf(float f) {
  unsigned int u = __float_as_uint(f);
  u += 0x7FFFu + ((u >> 16) & 1u);   // RNE
  return (unsigned short)(u >> 16);
}

// pack two fp32 -> [bf16(lo) | bf16(hi)<<16] (round-half-up, 0.5ulp)
__device__ __forceinline__ unsigned int pack2bf(float lo, float hi) {
  const unsigned int a = __float_as_uint(hi) + 0x8000u;
  const unsigned int b = __float_as_uint(lo) + 0x8000u;
  return __builtin_amdgcn_perm(a, b, 0x07060302u);
}

__device__ __forceinline__ f32x4 mfma16(short8 a, short8 b, f32x4 c) {
  return __builtin_amdgcn_mfma_f32_16x16x32_bf16(
      __builtin_bit_cast(bf16x8, a), __builtin_bit_cast(bf16x8, b), c, 0, 0, 0);
}

// async global->LDS, 16B per lane. LDS dest must be wave-uniform base + lane*16.
__device__ __forceinline__ void gload16(const void* g, void* lds) {
  auto gp = reinterpret_cast<const __attribute__((address_space(1))) unsigned int*>(
      reinterpret_cast<uintptr_t>(g));
  auto lp = reinterpret_cast<__attribute__((address_space(3))) unsigned int*>(
      static_cast<unsigned int>(reinterpret_cast<uintptr_t>(lds)));
  __builtin_amdgcn_global_load_lds(gp, lp, 16, 0, 0);
}

// build a bf16x8 fragment from two float4s (8 consecutive k-elements)
__device__ __forceinline__ short8 cvt_frag(float4 lo, float4 hi) {
  uint4 u;
  u.x = pack2bf(lo.x, lo.y); u.y = pack2bf(lo.z, lo.w);
  u.z = pack2bf(hi.x, hi.y); u.w = pack2bf(hi.z, hi.w);
  return __builtin_bit_cast(short8, u);
}

#define SBAR()  __builtin_amdgcn_s_barrier()
#define SCHED0() __builtin_amdgcn_sched_barrier(0)

// ---------------------------------------------------------------------------
// Kernel 1: router. One block per 4 tokens (grid 256). rw fetched once per
// block, reused x4. Wave w does softmax+top8 of token t0+w.
// ---------------------------------------------------------------------------
__global__ __launch_bounds__(256) void router_k(
    const float* __restrict__ x, const float* __restrict__ rw,
    float* __restrict__ topw, int* __restrict__ counts, int* __restrict__ rows)
{
  __shared__ float xs[4][H_];   // 32 KB
  __shared__ float lg[4][E_];
  const int t0  = blockIdx.x * 4;
  const int tid = threadIdx.x;
  for (int q = tid; q < 4 * (H_ / 4); q += 256) {
    const int tt = q >> 9;
    const int c  = q & 511;
    ((float4*)xs[tt])[c] = ((const float4*)(x + (size_t)(t0 + tt) * H_))[c];
  }
  __syncthreads();

  const int w = tid >> 6, lane = tid & 63;
  for (int ee = 0; ee < 16; ++ee) {
    const int e = w * 16 + ee;
    const float* wr = rw + (size_t)e * H_;
    float s0 = 0.f, s1 = 0.f, s2 = 0.f, s3 = 0.f;
    for (int h = lane; h < H_; h += 64) {
      const float wv = wr[h];
      s0 += wv * xs[0][h]; s1 += wv * xs[1][h];
      s2 += wv * xs[2][h]; s3 += wv * xs[3][h];
    }
    for (int off = 32; off; off >>= 1) {
      s0 += __shfl_xor(s0, off); s1 += __shfl_xor(s1, off);
      s2 += __shfl_xor(s2, off); s3 += __shfl_xor(s3, off);
    }
    if (lane == 0) { lg[0][e] = s0; lg[1][e] = s1; lg[2][e] = s2; lg[3][e] = s3; }
  }
  __syncthreads();

  {
    const int t = t0 + w;
    const float logit = lg[w][lane];
    float mx = logit;
    for (int off = 32; off; off >>= 1) mx = fmaxf(mx, __shfl_xor(mx, off));
    const float ex = expf(logit - mx);
    float sum = ex;
    for (int off = 32; off; off >>= 1) sum += __shfl_xor(sum, off);
    float p = ex / sum;
    for (int k = 0; k < TOPK; ++k) {
      float m = p; int mi = lane;
      for (int off = 32; off; off >>= 1) {
        const float om = __shfl_xor(m, off);
        const int   oi = __shfl_xor(mi, off);
        if (om > m || (om == m && oi < mi)) { m = om; mi = oi; }
      }
      if (lane == 0) {
        const int r = t * TOPK + k;
        topw[r] = m;
        const int pos = atomicAdd(&counts[mi], 1);
        rows[mi * CAP + pos] = r;
      }
      if (lane == mi) p = -1.f;
    }
  }
}

// ---------------------------------------------------------------------------
// Kernel 2: gate/up GEMM. grid=(E, I/64), 512 threads (8 waves: 4m x 2n).
// Counted-vmcnt pipeline: B (HBM weights) double-buffered; per iter
//   stage_B(k+1,buf^1) -> vmcnt(2) -> barrier -> MFMA(buf) -> barrier
//   -> stage_A(k+1)   [A = x rows, L3-resident, single buffer]
// Next tile's 2 B-loads stay in flight across the whole compute phase.
// ---------------------------------------------------------------------------
__global__ __launch_bounds__(512, 4) void gateup_k(
    const float* __restrict__ x, const float* __restrict__ wg,
    const float* __restrict__ wu, const float* __restrict__ topw,
    const int* __restrict__ counts, const int* __restrict__ rows,
    unsigned short* __restrict__ hmid)
{
  const int e  = blockIdx.x;
  const int n0 = blockIdx.y * GTN;
  const int cnt = counts[e];
  if (cnt == 0) return;
  const int* erows = rows + e * CAP;

  __shared__ __align__(16) float Al [GTM][GBK];      // 24KB single
  __shared__ __align__(16) float Bgl[2][GTN][GBK];   // 16KB dbuf
  __shared__ __align__(16) float Bul[2][GTN][GBK];   // 16KB dbuf

  const int tid  = threadIdx.x;
  const int wid  = tid >> 6, lane = tid & 63;
  const int wm   = wid >> 1, wn = wid & 1;        // 4x2 waves: 48 rows x 32 cols

  const float* wgE = wg + (size_t)e * I_ * H_ + (size_t)n0 * H_;
  const float* wuE = wu + (size_t)e * I_ * H_ + (size_t)n0 * H_;

  // staging geometry (linear LDS dest; source chunk XOR-swizzled)
  int arow[3], acoff[3];
#pragma unroll
  for (int q = 0; q < 3; ++q) {
    const int row = q * 64 + wid * 8 + (lane >> 3);
    arow[q]  = row;
    acoff[q] = ((lane & 7) ^ (row & 7)) * 4;
  }
  const int brow  = wid * 8 + (lane >> 3);
  const int bcoff = ((lane & 7) ^ (brow & 7)) * 4;

  char* AlB = (char*)Al; char* BgB = (char*)Bgl; char* BuB = (char*)Bul;
  const int ldsLane = wid * 1024 + lane * 16;

  // fragment LDS offsets (float units)
  int aoff[3][2], boff[2][2];
  const int h = lane >> 4;
#pragma unroll
  for (int mi = 0; mi < 3; ++mi) {
    const int r = wm * 48 + mi * 16 + (lane & 15);
    aoff[mi][0] = r * GBK + (((2*h    ) ^ (r & 7)) * 4);
    aoff[mi][1] = r * GBK + (((2*h + 1) ^ (r & 7)) * 4);
  }
#pragma unroll
  for (int ni = 0; ni < 2; ++ni) {
    const int r = wn * 32 + ni * 16 + (lane & 15);
    boff[ni][0] = r * GBK + (((2*h    ) ^ (r & 7)) * 4);
    boff[ni][1] = r * GBK + (((2*h + 1) ^ (r & 7)) * 4);
  }

  for (int m0 = 0; m0 < cnt; m0 += GTM) {
    const float* pa[3];
#pragma unroll
    for (int q = 0; q < 3; ++q) {
      int idx = m0 + arow[q]; if (idx >= cnt) idx = cnt - 1;
      pa[q] = x + (size_t)(erows[idx] >> 3) * H_ + acoff[q];
    }
    const float* pg = wgE + (size_t)brow * H_ + bcoff;
    const float* pu = wuE + (size_t)brow * H_ + bcoff;

    f32x4 accg[3][2], accu[3][2];
#pragma unroll
    for (int i = 0; i < 3; ++i)
#pragma unroll
      for (int j = 0; j < 2; ++j)
#pragma unroll
        for (int q = 0; q < 4; ++q) { accg[i][j][q] = 0.f; accu[i][j][q] = 0.f; }

    // prologue: B_0 (2 loads) then A_0 (3 loads)
    gload16(pg, BgB + ldsLane);
    gload16(pu, BuB + ldsLane);
    pg += GBK; pu += GBK;
    gload16(pa[0], AlB +     0 + ldsLane);
    gload16(pa[1], AlB +  8192 + ldsLane);
    gload16(pa[2], AlB + 16384 + ldsLane);
    pa[0] += GBK; pa[1] += GBK; pa[2] += GBK;

    int c = 0;
    for (int k0 = 0; k0 < H_; k0 += GBK) {
      const bool hasNext = (k0 + GBK < H_);
      if (hasNext) {            // stage B_{i+1} into buf c^1 (2 loads)
        gload16(pg, BgB + (c ^ 1) * 8192 + ldsLane);
        gload16(pu, BuB + (c ^ 1) * 8192 + ldsLane);
        pg += GBK; pu += GBK;
      }
      SCHED0();
      if (hasNext) asm volatile("s_waitcnt vmcnt(2)" ::: "memory");
      else         asm volatile("s_waitcnt vmcnt(0)" ::: "memory");
      SCHED0();
      SBAR();                   // tile i (A_i + B_i) visible to all waves
      {
        const float* AlC = (const float*)Al;
        const float* BgC = (const float*)Bgl + c * (GTN * GBK);
        const float* BuC = (const float*)Bul + c * (GTN * GBK);
        short8 af[3];
#pragma unroll
        for (int mi = 0; mi < 3; ++mi) {
          const float4 lo = *(const float4*)&AlC[aoff[mi][0]];
          const float4 hi = *(const float4*)&AlC[aoff[mi][1]];
          af[mi] = cvt_frag(lo, hi);
        }
#pragma unroll
        for (int ni = 0; ni < 2; ++ni) {
          const float4 glo = *(const float4*)&BgC[boff[ni][0]];
          const float4 ghi = *(const float4*)&BgC[boff[ni][1]];
          const short8 bg = cvt_frag(glo, ghi);
          const float4 ulo = *(const float4*)&BuC[boff[ni][0]];
          const float4 uhi = *(const float4*)&BuC[boff[ni][1]];
          const short8 bu = cvt_frag(ulo, uhi);
#pragma unroll
          for (int mi = 0; mi < 3; ++mi) {
            accg[mi][ni] = mfma16(af[mi], bg, accg[mi][ni]);
            accu[mi][ni] = mfma16(af[mi], bu, accu[mi][ni]);
          }
        }
      }
      SBAR();                   // all waves done reading Al + buf c
      SCHED0();
      if (hasNext) {            // stage A_{i+1} (3 loads) in compute shadow
        gload16(pa[0], AlB +     0 + ldsLane);
        gload16(pa[1], AlB +  8192 + ldsLane);
        gload16(pa[2], AlB + 16384 + ldsLane);
        pa[0] += GBK; pa[1] += GBK; pa[2] += GBK;
      }
      c ^= 1;
    }
    // epilogue: h = silu(g)*u*cw -> bf16
#pragma unroll
    for (int mi = 0; mi < 3; ++mi)
#pragma unroll
      for (int ni = 0; ni < 2; ++ni)
#pragma unroll
        for (int j = 0; j < 4; ++j) {
          const int ml = wm * 48 + mi * 16 + (lane >> 4) * 4 + j;
          if (m0 + ml < cnt) {
            const int r = erows[m0 + ml];
            const float cw = topw[r];
            const float g = accg[mi][ni][j], uu = accu[mi][ni][j];
            const float hv = g / (1.f + __expf(-g)) * uu * cw;
            hmid[(size_t)r * I_ + n0 + wn * 32 + ni * 16 + (lane & 15)] = f2bf(hv);
          }
        }
  }
}

// ---------------------------------------------------------------------------
// Kernel 3: down GEMM. grid=(E, H/64). Same counted-vmcnt pipeline:
// B (wd, HBM) dbuf with vmcnt(1); A (hmid, L2/L3) single-buffered, staged
// in compute shadow. A-round1 only on waves 0-3 (vmcnt count still uniform:
// only B's 1 load allowed outstanding).
// ---------------------------------------------------------------------------
__global__ __launch_bounds__(512, 4) void down_k(
    const unsigned short* __restrict__ hmid, const float* __restrict__ wd,
    const int* __restrict__ counts, const int* __restrict__ rows,
    float* __restrict__ outp, const int atomicMode)
{
  const int e  = blockIdx.x;
  const int n0 = blockIdx.y * GTN;
  const int cnt = counts[e];
  if (cnt == 0) return;
  const int* erows = rows + e * CAP;

  __shared__ __align__(16) unsigned short Al[GTM][GBK];  // 12KB single
  __shared__ __align__(16) float          Bl[2][GTN][GBK]; // 16KB dbuf

  const int tid  = threadIdx.x;
  const int wid  = tid >> 6, lane = tid & 63;
  const int wm   = wid >> 1, wn = wid & 1;

  const float* wdE = wd + (size_t)e * H_ * I_ + (size_t)n0 * I_;

  const int arow0 = wid * 16 + (lane >> 2);
  const int arow1 = 128 + arow0;
  const int ac0 = (((lane & 3) ^ ((arow0 >> 1) & 3))) * 8;  // ushort offset
  const int ac1 = (((lane & 3) ^ ((arow1 >> 1) & 3))) * 8;
  const int brow  = wid * 8 + (lane >> 3);
  const int bcoff = ((lane & 7) ^ (brow & 7)) * 4;

  char* AlB = (char*)Al; char* BlB = (char*)Bl;
  const int ldsLane = wid * 1024 + lane * 16;

  int aoff[3], boff[2][2];
  const int h = lane >> 4;
#pragma unroll
  for (int mi = 0; mi < 3; ++mi) {
    const int r = wm * 48 + mi * 16 + (lane & 15);
    aoff[mi] = r * GBK + ((h ^ ((r >> 1) & 3)) * 8);        // ushort units
  }
#pragma unroll
  for (int ni = 0; ni < 2; ++ni) {
    const int r = wn * 32 + ni * 16 + (lane & 15);
    boff[ni][0] = r * GBK + (((2*h    ) ^ (r & 7)) * 4);
    boff[ni][1] = r * GBK + (((2*h + 1) ^ (r & 7)) * 4);
  }

  for (int m0 = 0; m0 < cnt; m0 += GTM) {
    int i0 = m0 + arow0; if (i0 >= cnt) i0 = cnt - 1;
    int i1 = m0 + arow1; if (i1 >= cnt) i1 = cnt - 1;
    const unsigned short* pa0 = hmid + (size_t)erows[i0] * I_ + ac0;
    const unsigned short* pa1 = hmid + (size_t)erows[i1] * I_ + ac1;
    const float* pb = wdE + (size_t)brow * I_ + bcoff;

    f32x4 acc[3][2];
#pragma unroll
    for (int i = 0; i < 3; ++i)
#pragma unroll
      for (int j = 0; j < 2; ++j)
#pragma unroll
        for (int q = 0; q < 4; ++q) acc[i][j][q] = 0.f;

    // prologue: B_0 (1 load) then A_0 (1-2 loads)
    gload16(pb, BlB + ldsLane);
    pb += GBK;
    gload16(pa0, AlB + ldsLane);
    if (wid < 4) gload16(pa1, AlB + 8192 + ldsLane);
    pa0 += GBK; pa1 += GBK;

    int c = 0;
    for (int k0 = 0; k0 < I_; k0 += GBK) {
      const bool hasNext = (k0 + GBK < I_);
      if (hasNext) {
        gload16(pb, BlB + (c ^ 1) * 8192 + ldsLane);
        pb += GBK;
      }
      SCHED0();
      if (hasNext) asm volatile("s_waitcnt vmcnt(1)" ::: "memory");
      else         asm volatile("s_waitcnt vmcnt(0)" ::: "memory");
      SCHED0();
      SBAR();
      {
        const unsigned short* AlC = (const unsigned short*)Al;
        const float*          BlC = (const float*)Bl + c * (GTN * GBK);
        short8 af[3];
#pragma unroll
        for (int mi = 0; mi < 3; ++mi)
          af[mi] = *(const short8*)&AlC[aoff[mi]];
#pragma unroll
        for (int ni = 0; ni < 2; ++ni) {
          const float4 blo = *(const float4*)&BlC[boff[ni][0]];
          const float4 bhi = *(const float4*)&BlC[boff[ni][1]];
          const short8 bw = cvt_frag(blo, bhi);
#pragma unroll
          for (int mi = 0; mi < 3; ++mi)
            acc[mi][ni] = mfma16(af[mi], bw, acc[mi][ni]);
        }
      }
      SBAR();
      SCHED0();
      if (hasNext) {
        gload16(pa0, AlB + ldsLane);
        if (wid < 4) gload16(pa1, AlB + 8192 + ldsLane);
        pa0 += GBK; pa1 += GBK;
      }
      c ^= 1;
    }
#pragma unroll
    for (int mi = 0; mi < 3; ++mi)
#pragma unroll
      for (int ni = 0; ni < 2; ++ni)
#pragma unroll
        for (int j = 0; j < 4; ++j) {
          const int ml = wm * 48 + mi * 16 + (lane >> 4) * 4 + j;
          if (m0 + ml < cnt) {
            const int r = erows[m0 + ml];
            const int col = n0 + wn * 32 + ni * 16 + (lane & 15);
            if (atomicMode) atomicAdd(&outp[(size_t)(r >> 3) * H_ + col], acc[mi][ni][j]);
            else            outp[(size_t)r * H_ + col] = acc[mi][ni][j];
          }
        }
  }
}

// ---------------------------------------------------------------------------
// Kernel 4: combine partials over k=0..7 (deterministic fixed-order sum)
// ---------------------------------------------------------------------------
__global__ __launch_bounds__(256) void combine_k(
    const float* __restrict__ partial, float* __restrict__ out)
{
  const int idx = blockIdx.x * 256 + threadIdx.x;
  const int t = idx >> 9;
  const int c = idx & 511;
  float4 s; s.x = 0.f; s.y = 0.f; s.z = 0.f; s.w = 0.f;
#pragma unroll
  for (int k = 0; k < TOPK; ++k) {
    const float4 v = *(const float4*)(partial + (size_t)(t * TOPK + k) * H_ + c * 4);
    s.x += v.x; s.y += v.y; s.z += v.z; s.w += v.w;
  }
  *(float4*)(out + (size_t)t * H_ + c * 4) = s;
}

// ---------------------------------------------------------------------------
extern "C" void kernel_launch(void* const* d_in, const int* in_sizes, int n_in,
                              void* d_out, int out_size, void* d_ws, size_t ws_size,
                              hipStream_t stream)
{
  const float* x  = (const float*)d_in[0];
  const float* rw = (const float*)d_in[1];
  const float* wg = (const float*)d_in[2];
  const float* wu = (const float*)d_in[3];
  const float* wd = (const float*)d_in[4];
  float* out = (float*)d_out;

  char* ws = (char*)d_ws;
  const size_t OFF_TOPW = 1024;
  const size_t OFF_ROWS = OFF_TOPW + (size_t)T_ * TOPK * 4;
  const size_t OFF_HMID = OFF_ROWS + (size_t)E_ * CAP * 4;
  const size_t OFF_PART = OFF_HMID + (size_t)T_ * TOPK * I_ * 2;
  const size_t TOTAL    = OFF_PART + (size_t)T_ * TOPK * H_ * 4;

  int*   counts = (int*)ws;
  float* topw   = (float*)(ws + OFF_TOPW);
  int*   rows   = (int*)(ws + OFF_ROWS);
  unsigned short* hmid = (unsigned short*)(ws + OFF_HMID);
  float* partial = (float*)(ws + OFF_PART);

  const int usePartial = (ws_size >= TOTAL) ? 1 : 0;

  hipMemsetAsync(counts, 0, E_ * sizeof(int), stream);
  router_k<<<T_ / 4, 256, 0, stream>>>(x, rw, topw, counts, rows);
  gateup_k<<<dim3(E_, I_ / GTN), 512, 0, stream>>>(x, wg, wu, topw, counts, rows, hmid);
  if (usePartial) {
    down_k<<<dim3(E_, H_ / GTN), 512, 0, stream>>>(hmid, wd, counts, rows, partial, 0);
    combine_k<<<(T_ * H_ / 4) / 256, 256, 0, stream>>>(partial, out);
  } else {
    hipMemsetAsync(out, 0, (size_t)out_size * sizeof(float), stream);
    down_k<<<dim3(E_, H_ / GTN), 512, 0, stream>>>(hmid, wd, counts, rows, out, 1);
  }
}